// Round 4
// baseline (202.246 us; speedup 1.0000x reference)
//
#include <hip/hip_runtime.h>
#include <hip/hip_bf16.h>

#define B_ROWS 131072
#define H 128
#define BM 32
#define TILES 8
#define NBLK (B_ROWS / (BM * TILES))   // 512 blocks

typedef __bf16 bf16x8 __attribute__((ext_vector_type(8)));
typedef float f32x4 __attribute__((ext_vector_type(4)));

struct WPtrs {
    const float* wx[4];
    const float* wh[4];
    const float* bx[4];
    const float* bh[4];
};

// Wcat[n][k]: n = gate*128 + hidden_unit, k in [0,256) = [X-k | h-k]. bsum[n] = bx+bh.
__global__ __launch_bounds__(256) void prep_weights(WPtrs p, __bf16* __restrict__ wcat,
                                                    float* __restrict__ bsum) {
    int n = blockIdx.x;      // 0..511
    int k = threadIdx.x;     // 0..255
    int g = n >> 7, r = n & 127;
    float v = (k < H) ? p.wx[g][r * H + k] : p.wh[g][r * H + (k - H)];
    wcat[n * 256 + k] = (__bf16)v;
    if (k == 0) bsum[n] = p.bx[g][r] + p.bh[g][r];
}

__global__ __launch_bounds__(512, 4) void lstm_fused(
    const float* __restrict__ X, const float* __restrict__ Hp, const float* __restrict__ Cp,
    const __bf16* __restrict__ Wcat, const float* __restrict__ Bsum,
    float* __restrict__ out)
{
    __shared__ char  alds[BM * 512];        // 16.4 KB bf16 [X|h] tile, XOR-swizzled
    __shared__ float cplds[BM][132];        // 16.9 KB c_prev (coalesced in -> scattered read)
    __shared__ float hclds[2][BM][132];     // 33.8 KB h,c    (scattered write -> coalesced out)
    // total 67 KB -> 2 blocks/CU; VGPR capped at 128 by launch_bounds -> 16 waves/CU

    const int t = threadIdx.x;
    const int lane = t & 63;
    const int wv = t >> 6;                   // wave 0..7 -> hidden cols [wv*16, wv*16+16)
    const int l16 = lane & 15;
    const int kg = lane >> 4;                // 0..3
    const long base = (long)blockIdx.x * (BM * TILES);
    const long c_off = (long)B_ROWS * H;

    const int j = wv * 16 + l16;             // this lane's hidden column (B-frag col)
    const __bf16* wbase = Wcat + (long)j * 256 + kg * 8;

    float bias[4];
#pragma unroll
    for (int g = 0; g < 4; ++g) bias[g] = Bsum[g * H + j];

    // coalesced map: thread t handles rows r_q0/r_q1, float4-col c4
    const int r_q0 = t >> 5;                 // 0..15
    const int r_q1 = 16 + (t >> 5);          // 16..31
    const int c4 = t & 31;

    float4 sx[2], sh[2], scp[2];

    // prologue: issue tile-0 loads
    sx[0]  = *(const float4*)(X  + (base + r_q0) * H + c4 * 4);
    sh[0]  = *(const float4*)(Hp + (base + r_q0) * H + c4 * 4);
    sx[1]  = *(const float4*)(X  + (base + r_q1) * H + c4 * 4);
    sh[1]  = *(const float4*)(Hp + (base + r_q1) * H + c4 * 4);
    scp[0] = *(const float4*)(Cp + (base + r_q0) * H + c4 * 4);
    scp[1] = *(const float4*)(Cp + (base + r_q1) * H + c4 * 4);

    for (int tile = 0; tile < TILES; ++tile) {
        const long r0 = base + tile * BM;

        // ---- Phase A: staged regs -> LDS (A-tile bf16 swizzled; Cp float4) ----
#pragma unroll
        for (int q = 0; q < 2; ++q) {
            int row = q ? r_q1 : r_q0;
            int swz = (row & 7) << 4;
            union { __bf16 b[4]; unsigned long long u; } px, ph;
            float4 vx = sx[q], vh = sh[q];
            px.b[0] = (__bf16)vx.x; px.b[1] = (__bf16)vx.y;
            px.b[2] = (__bf16)vx.z; px.b[3] = (__bf16)vx.w;
            ph.b[0] = (__bf16)vh.x; ph.b[1] = (__bf16)vh.y;
            ph.b[2] = (__bf16)vh.z; ph.b[3] = (__bf16)vh.w;
            *(unsigned long long*)(alds + row * 512 + ((c4 * 8) ^ swz)) = px.u;
            *(unsigned long long*)(alds + row * 512 + ((256 + c4 * 8) ^ swz)) = ph.u;
            *(f32x4*)&cplds[row][c4 * 4] = *(f32x4*)&scp[q];
        }
        __syncthreads();

        // ---- Phase B: prefetch next tile; MFMA; in-lane epilogue; scatter h,c ----
        if (tile + 1 < TILES) {
            long rn = r0 + BM;
            sx[0]  = *(const float4*)(X  + (rn + r_q0) * H + c4 * 4);
            sh[0]  = *(const float4*)(Hp + (rn + r_q0) * H + c4 * 4);
            sx[1]  = *(const float4*)(X  + (rn + r_q1) * H + c4 * 4);
            sh[1]  = *(const float4*)(Hp + (rn + r_q1) * H + c4 * 4);
            scp[0] = *(const float4*)(Cp + (rn + r_q0) * H + c4 * 4);
            scp[1] = *(const float4*)(Cp + (rn + r_q1) * H + c4 * 4);
        }

        f32x4 acc[4][2] = {};
#pragma unroll
        for (int kc = 0; kc < 8; ++kc) {
            bf16x8 a[2];
#pragma unroll
            for (int rt = 0; rt < 2; ++rt) {
                int row = rt * 16 + l16;
                int off = row * 512 + ((kc * 64 + kg * 16) ^ ((row & 7) << 4));
                a[rt] = *(const bf16x8*)(alds + off);
            }
#pragma unroll
            for (int g = 0; g < 4; ++g) {
                bf16x8 b = *(const bf16x8*)(wbase + g * (128 * 256) + kc * 32);
                acc[g][0] = __builtin_amdgcn_mfma_f32_16x16x32_bf16(a[0], b, acc[g][0], 0, 0, 0);
                acc[g][1] = __builtin_amdgcn_mfma_f32_16x16x32_bf16(a[1], b, acc[g][1], 0, 0, 0);
            }
        }

        // all 4 gates are lane-local: do the LSTM math here, at scatter layout
#pragma unroll
        for (int rt = 0; rt < 2; ++rt) {
#pragma unroll
            for (int r = 0; r < 4; ++r) {
                int row = rt * 16 + kg * 4 + r;        // C/D layout: row=(lane>>4)*4+reg
                float cp = cplds[row][j];
                float f  = acc[0][rt][r] + bias[0];
                float ii = acc[1][rt][r] + bias[1];
                float cl = acc[2][rt][r] + bias[2];
                float oo = acc[3][rt][r] + bias[3];
                float ft = 1.0f / (1.0f + __expf(-f));
                float it = 1.0f / (1.0f + __expf(-ii));
                float cc = 1.0f - 2.0f / (__expf(2.0f * cl) + 1.0f);
                float ot = 1.0f / (1.0f + __expf(-oo));
                float ct = ft * cp + it * cc;
                float th = 1.0f - 2.0f / (__expf(2.0f * ct) + 1.0f);
                hclds[0][row][j] = ot * th;            // 2-way bank alias only (free)
                hclds[1][row][j] = ct;
            }
        }
        __syncthreads();

        // ---- Phase C: coalesced float4 read + store ----
#pragma unroll
        for (int q = 0; q < 2; ++q) {
            int row = q ? r_q1 : r_q0;
            f32x4 hv = *(const f32x4*)&hclds[0][row][c4 * 4];
            f32x4 cv = *(const f32x4*)&hclds[1][row][c4 * 4];
            *(f32x4*)(out + (r0 + row) * H + c4 * 4) = hv;
            *(f32x4*)(out + c_off + (r0 + row) * H + c4 * 4) = cv;
        }
        // next Phase A writes alds/cplds (reads of those finished before bar2);
        // next hclds writes are fenced by next bar1.
    }
}

extern "C" void kernel_launch(void* const* d_in, const int* in_sizes, int n_in,
                              void* d_out, int out_size, void* d_ws, size_t ws_size,
                              hipStream_t stream) {
    const float* X  = (const float*)d_in[0];
    const float* Hp = (const float*)d_in[1];
    const float* Cp = (const float*)d_in[2];
    WPtrs p;
    p.wx[0] = (const float*)d_in[3];  p.bx[0] = (const float*)d_in[4];
    p.wh[0] = (const float*)d_in[5];  p.bh[0] = (const float*)d_in[6];
    p.wx[1] = (const float*)d_in[7];  p.bx[1] = (const float*)d_in[8];
    p.wh[1] = (const float*)d_in[9];  p.bh[1] = (const float*)d_in[10];
    p.wx[2] = (const float*)d_in[11]; p.bx[2] = (const float*)d_in[12];
    p.wh[2] = (const float*)d_in[13]; p.bh[2] = (const float*)d_in[14];
    p.wx[3] = (const float*)d_in[15]; p.bx[3] = (const float*)d_in[16];
    p.wh[3] = (const float*)d_in[17]; p.bh[3] = (const float*)d_in[18];

    __bf16* wcat = (__bf16*)d_ws;
    float*  bsum = (float*)((char*)d_ws + 512 * 256 * 2);

    prep_weights<<<512, 256, 0, stream>>>(p, wcat, bsum);
    lstm_fused<<<NBLK, 512, 0, stream>>>(X, Hp, Cp, wcat, bsum, (float*)d_out);
}

// Round 5
// 117.879 us; speedup vs baseline: 1.7157x; 1.7157x over previous
//
#include <hip/hip_runtime.h>
#include <hip/hip_bf16.h>

#define B_ROWS 131072
#define H 128
#define BM 32
#define TILES 8
#define NBLK (B_ROWS / (BM * TILES))   // 512 blocks

typedef __bf16 bf16x8 __attribute__((ext_vector_type(8)));
typedef float f32x4 __attribute__((ext_vector_type(4)));

struct WPtrs {
    const float* wx[4];
    const float* wh[4];
    const float* bx[4];
    const float* bh[4];
};

// Wcat[n][k]: n = gate*128 + hidden_unit, k in [0,256) = [X-k | h-k]. bsum[n] = bx+bh.
__global__ __launch_bounds__(256) void prep_weights(WPtrs p, __bf16* __restrict__ wcat,
                                                    float* __restrict__ bsum) {
    int n = blockIdx.x;      // 0..511
    int k = threadIdx.x;     // 0..255
    int g = n >> 7, r = n & 127;
    float v = (k < H) ? p.wx[g][r * H + k] : p.wh[g][r * H + (k - H)];
    wcat[n * 256 + k] = (__bf16)v;
    if (k == 0) bsum[n] = p.bx[g][r] + p.bh[g][r];
}

// launch_bounds 2nd arg = min BLOCKS/CU (CUDA-like on hipcc): (512,2) -> 16 waves/CU
// -> VGPR cap 128 (R3 compiled at 116, no spill). (512,4) caused a 64-VGPR spill (R2/R4).
__global__ __launch_bounds__(512, 2) void lstm_fused(
    const float* __restrict__ X, const float* __restrict__ Hp, const float* __restrict__ Cp,
    const __bf16* __restrict__ Wcat, const float* __restrict__ Bsum,
    float* __restrict__ out)
{
    __shared__ char  alds[BM * 512];        // 16.4 KB bf16 [X|h] tile, XOR-swizzled
    __shared__ float cplds[BM][132];        // 16.9 KB c_prev (coalesced in -> scattered read)
    __shared__ float hclds[2][BM][132];     // 33.8 KB h,c    (scattered write -> coalesced out)
    // total 67 KB -> 2 blocks/CU (LDS-limited)

    const int t = threadIdx.x;
    const int lane = t & 63;
    const int wv = t >> 6;                   // wave 0..7 -> hidden cols [wv*16, wv*16+16)
    const int l16 = lane & 15;
    const int kg = lane >> 4;                // 0..3
    const long base = (long)blockIdx.x * (BM * TILES);
    const long c_off = (long)B_ROWS * H;

    const int j = wv * 16 + l16;             // this lane's hidden column (B-frag col)
    const __bf16* wbase = Wcat + (long)j * 256 + kg * 8;

    float bias[4];
#pragma unroll
    for (int g = 0; g < 4; ++g) bias[g] = Bsum[g * H + j];

    // coalesced map: thread t handles rows r_q0/r_q1, float4-col c4
    const int r_q0 = t >> 5;                 // 0..15
    const int r_q1 = 16 + (t >> 5);          // 16..31
    const int c4 = t & 31;

    float4 sx[2], sh[2], scp[2];

    // prologue: issue tile-0 loads
    sx[0]  = *(const float4*)(X  + (base + r_q0) * H + c4 * 4);
    sh[0]  = *(const float4*)(Hp + (base + r_q0) * H + c4 * 4);
    sx[1]  = *(const float4*)(X  + (base + r_q1) * H + c4 * 4);
    sh[1]  = *(const float4*)(Hp + (base + r_q1) * H + c4 * 4);
    scp[0] = *(const float4*)(Cp + (base + r_q0) * H + c4 * 4);
    scp[1] = *(const float4*)(Cp + (base + r_q1) * H + c4 * 4);

    for (int tile = 0; tile < TILES; ++tile) {
        const long r0 = base + tile * BM;

        // ---- Phase A: staged regs -> LDS (A-tile bf16 swizzled; Cp float4) ----
#pragma unroll
        for (int q = 0; q < 2; ++q) {
            int row = q ? r_q1 : r_q0;
            int swz = (row & 7) << 4;
            union { __bf16 b[4]; unsigned long long u; } px, ph;
            float4 vx = sx[q], vh = sh[q];
            px.b[0] = (__bf16)vx.x; px.b[1] = (__bf16)vx.y;
            px.b[2] = (__bf16)vx.z; px.b[3] = (__bf16)vx.w;
            ph.b[0] = (__bf16)vh.x; ph.b[1] = (__bf16)vh.y;
            ph.b[2] = (__bf16)vh.z; ph.b[3] = (__bf16)vh.w;
            *(unsigned long long*)(alds + row * 512 + ((c4 * 8) ^ swz)) = px.u;
            *(unsigned long long*)(alds + row * 512 + ((256 + c4 * 8) ^ swz)) = ph.u;
            *(f32x4*)&cplds[row][c4 * 4] = *(f32x4*)&scp[q];
        }
        __syncthreads();

        // ---- Phase B: prefetch next tile; MFMA; in-lane epilogue; scatter h,c ----
        if (tile + 1 < TILES) {
            long rn = r0 + BM;
            sx[0]  = *(const float4*)(X  + (rn + r_q0) * H + c4 * 4);
            sh[0]  = *(const float4*)(Hp + (rn + r_q0) * H + c4 * 4);
            sx[1]  = *(const float4*)(X  + (rn + r_q1) * H + c4 * 4);
            sh[1]  = *(const float4*)(Hp + (rn + r_q1) * H + c4 * 4);
            scp[0] = *(const float4*)(Cp + (rn + r_q0) * H + c4 * 4);
            scp[1] = *(const float4*)(Cp + (rn + r_q1) * H + c4 * 4);
        }

        f32x4 acc[4][2] = {};
#pragma unroll
        for (int kc = 0; kc < 8; ++kc) {
            bf16x8 a[2];
#pragma unroll
            for (int rt = 0; rt < 2; ++rt) {
                int row = rt * 16 + l16;
                int off = row * 512 + ((kc * 64 + kg * 16) ^ ((row & 7) << 4));
                a[rt] = *(const bf16x8*)(alds + off);
            }
#pragma unroll
            for (int g = 0; g < 4; ++g) {
                bf16x8 b = *(const bf16x8*)(wbase + g * (128 * 256) + kc * 32);
                acc[g][0] = __builtin_amdgcn_mfma_f32_16x16x32_bf16(a[0], b, acc[g][0], 0, 0, 0);
                acc[g][1] = __builtin_amdgcn_mfma_f32_16x16x32_bf16(a[1], b, acc[g][1], 0, 0, 0);
            }
        }

        // all 4 gates are lane-local: do the LSTM math here, at scatter layout
#pragma unroll
        for (int rt = 0; rt < 2; ++rt) {
#pragma unroll
            for (int r = 0; r < 4; ++r) {
                int row = rt * 16 + kg * 4 + r;        // C/D layout: row=(lane>>4)*4+reg
                float cp = cplds[row][j];
                float f  = acc[0][rt][r] + bias[0];
                float ii = acc[1][rt][r] + bias[1];
                float cl = acc[2][rt][r] + bias[2];
                float oo = acc[3][rt][r] + bias[3];
                float ft = 1.0f / (1.0f + __expf(-f));
                float it = 1.0f / (1.0f + __expf(-ii));
                float cc = 1.0f - 2.0f / (__expf(2.0f * cl) + 1.0f);
                float ot = 1.0f / (1.0f + __expf(-oo));
                float ct = ft * cp + it * cc;
                float th = 1.0f - 2.0f / (__expf(2.0f * ct) + 1.0f);
                hclds[0][row][j] = ot * th;            // 2-way bank alias only (free)
                hclds[1][row][j] = ct;
            }
        }
        __syncthreads();

        // ---- Phase C: coalesced float4 read + store ----
#pragma unroll
        for (int q = 0; q < 2; ++q) {
            int row = q ? r_q1 : r_q0;
            f32x4 hv = *(const f32x4*)&hclds[0][row][c4 * 4];
            f32x4 cv = *(const f32x4*)&hclds[1][row][c4 * 4];
            *(f32x4*)(out + (r0 + row) * H + c4 * 4) = hv;
            *(f32x4*)(out + c_off + (r0 + row) * H + c4 * 4) = cv;
        }
        // next Phase A writes alds/cplds (reads of those finished before bar2);
        // next hclds writes are fenced by next bar1.
    }
}

extern "C" void kernel_launch(void* const* d_in, const int* in_sizes, int n_in,
                              void* d_out, int out_size, void* d_ws, size_t ws_size,
                              hipStream_t stream) {
    const float* X  = (const float*)d_in[0];
    const float* Hp = (const float*)d_in[1];
    const float* Cp = (const float*)d_in[2];
    WPtrs p;
    p.wx[0] = (const float*)d_in[3];  p.bx[0] = (const float*)d_in[4];
    p.wh[0] = (const float*)d_in[5];  p.bh[0] = (const float*)d_in[6];
    p.wx[1] = (const float*)d_in[7];  p.bx[1] = (const float*)d_in[8];
    p.wh[1] = (const float*)d_in[9];  p.bh[1] = (const float*)d_in[10];
    p.wx[2] = (const float*)d_in[11]; p.bx[2] = (const float*)d_in[12];
    p.wh[2] = (const float*)d_in[13]; p.bh[2] = (const float*)d_in[14];
    p.wx[3] = (const float*)d_in[15]; p.bx[3] = (const float*)d_in[16];
    p.wh[3] = (const float*)d_in[17]; p.bh[3] = (const float*)d_in[18];

    __bf16* wcat = (__bf16*)d_ws;
    float*  bsum = (float*)((char*)d_ws + 512 * 256 * 2);

    prep_weights<<<512, 256, 0, stream>>>(p, wcat, bsum);
    lstm_fused<<<NBLK, 512, 0, stream>>>(X, Hp, Cp, wcat, bsum, (float*)d_out);
}